// Round 10
// baseline (277.924 us; speedup 1.0000x reference)
//
#include <hip/hip_runtime.h>
#include <math.h>

// Problem constants (fixed by the reference).
#define B_ 256
#define J_ 10
#define I_ 1152
#define N_ 16
#define TPB 512     // 8 waves; one block per batch element; grid = 256 = 1/CU
#define STEPS 18    // 64 i-rows per step
#define CHUNK_F (2 * I_ * N_)  // floats between j-pairs (j,j+1) in u
#define STEPF (64 * N_)        // floats per 64-row step stride
#define WBUF 1280              // floats per wave staging buffer (5 KB)

typedef const __attribute__((address_space(1))) void* gas_t;
typedef __attribute__((address_space(3))) void* las_t;

__device__ __forceinline__ float4 ld4(const float* p) {
  return *(const float4*)p;
}

#define WAIT_VM(N)                                           \
  do {                                                       \
    asm volatile("s_waitcnt vmcnt(%0)" ::"i"(N) : "memory"); \
    __builtin_amdgcn_sched_barrier(0);                       \
  } while (0)

#define WAIT_LGKM0                                     \
  do {                                                 \
    asm volatile("s_waitcnt lgkmcnt(0)" ::: "memory"); \
    __builtin_amdgcn_sched_barrier(0);                 \
  } while (0)

// One wave-step DMA: 5 x global_load_lds (16B/lane, 1 KB each); k covers the
// j-pair (2k,2k+1) x 8 rows x 16 n. LDS dest wave-uniform base + lane*16.
#define STAGE1(LW, P, K)                                       \
  __builtin_amdgcn_global_load_lds(                            \
      (gas_t)(g0 + (size_t)(K)*CHUNK_F + (size_t)(P)*STEPF),   \
      (las_t)((LW) + (K)*256), 16, 0, 0)
#define STAGE(LW, P)     \
  do {                   \
    STAGE1(LW, P, 0);    \
    STAGE1(LW, P, 1);    \
    STAGE1(LW, P, 2);    \
    STAGE1(LW, P, 3);    \
    STAGE1(LW, P, 4);    \
  } while (0)

// Element (j, row rc, quad q) lives at float offset j*128 + rc*16 + q*4.
#define READT(LW)                                             \
  do {                                                        \
    const float* _rp = (LW) + jh * 640 + rc * 16 + q * 4;     \
    t0 = ld4(_rp);                                            \
    t1 = ld4(_rp + 128);                                      \
    t2 = ld4(_rp + 256);                                      \
    t3 = ld4(_rp + 384);                                      \
    t4 = ld4(_rp + 512);                                      \
  } while (0)

#define BODY_SUM()                                                  \
  do {                                                              \
    acc0.x += t0.x; acc0.y += t0.y; acc0.z += t0.z; acc0.w += t0.w; \
    acc1.x += t1.x; acc1.y += t1.y; acc1.z += t1.z; acc1.w += t1.w; \
    acc2.x += t2.x; acc2.y += t2.y; acc2.z += t2.z; acc2.w += t2.w; \
    acc3.x += t3.x; acc3.y += t3.y; acc3.z += t3.z; acc3.w += t3.w; \
    acc4.x += t4.x; acc4.y += t4.y; acc4.z += t4.z; acc4.w += t4.w; \
  } while (0)

#define DOTW(T, W) ((T).x*(W).x + (T).y*(W).y + (T).z*(W).z + (T).w*(W).w)

// softmax over j (no max-subtract: |u.w| = O(10) << 88; masked j -> exp = 0).
// Each thread owns 5 j's (half jh); denominator combined via shfl_xor(.,4).
#define BODY_W()                                                       \
  do {                                                                 \
    float d0 = DOTW(t0, wq0), d1 = DOTW(t1, wq1), d2 = DOTW(t2, wq2),  \
          d3 = DOTW(t3, wq3), d4 = DOTW(t4, wq4);                      \
    d0 += __shfl_xor(d0, 1); d0 += __shfl_xor(d0, 2);                  \
    d1 += __shfl_xor(d1, 1); d1 += __shfl_xor(d1, 2);                  \
    d2 += __shfl_xor(d2, 1); d2 += __shfl_xor(d2, 2);                  \
    d3 += __shfl_xor(d3, 1); d3 += __shfl_xor(d3, 2);                  \
    d4 += __shfl_xor(d4, 1); d4 += __shfl_xor(d4, 2);                  \
    d0 = __expf(d0 + mv0); d1 = __expf(d1 + mv1);                      \
    d2 = __expf(d2 + mv2); d3 = __expf(d3 + mv3);                      \
    d4 = __expf(d4 + mv4);                                             \
    float se = d0 + d1 + d2 + d3 + d4;                                 \
    se += __shfl_xor(se, 4);                                           \
    const float inv = 1.f / se;                                        \
    d0 *= inv; d1 *= inv; d2 *= inv; d3 *= inv; d4 *= inv;             \
    acc0.x = fmaf(d0, t0.x, acc0.x); acc0.y = fmaf(d0, t0.y, acc0.y);  \
    acc0.z = fmaf(d0, t0.z, acc0.z); acc0.w = fmaf(d0, t0.w, acc0.w);  \
    acc1.x = fmaf(d1, t1.x, acc1.x); acc1.y = fmaf(d1, t1.y, acc1.y);  \
    acc1.z = fmaf(d1, t1.z, acc1.z); acc1.w = fmaf(d1, t1.w, acc1.w);  \
    acc2.x = fmaf(d2, t2.x, acc2.x); acc2.y = fmaf(d2, t2.y, acc2.y);  \
    acc2.z = fmaf(d2, t2.z, acc2.z); acc2.w = fmaf(d2, t2.w, acc2.w);  \
    acc3.x = fmaf(d3, t3.x, acc3.x); acc3.y = fmaf(d3, t3.y, acc3.y);  \
    acc3.z = fmaf(d3, t3.z, acc3.z); acc3.w = fmaf(d3, t3.w, acc3.w);  \
    acc4.x = fmaf(d4, t4.x, acc4.x); acc4.y = fmaf(d4, t4.y, acc4.y);  \
    acc4.z = fmaf(d4, t4.z, acc4.z); acc4.w = fmaf(d4, t4.w, acc4.w);  \
  } while (0)

#define HALF(LW, NEXTP, VMC, BODY)       \
  do {                                   \
    WAIT_VM(VMC);                        \
    READT(LW);                           \
    WAIT_LGKM0;                          \
    if ((NEXTP) < STEPS) STAGE(LW, NEXTP); \
    BODY();                              \
  } while (0)

#define STEP2(P, BODY)                                   \
  HALF(lA, (P) + 2, 5, BODY);                            \
  HALF(lB, (P) + 3, (((P) + 2 < STEPS) ? 5 : 0), BODY);

#define RUN_PASS(BODY)                                         \
  do {                                                         \
    acc0 = make_float4(0.f, 0.f, 0.f, 0.f);                    \
    acc1 = acc0; acc2 = acc0; acc3 = acc0; acc4 = acc0;        \
    STAGE(lA, 0);                                              \
    STAGE(lB, 1);                                              \
    STEP2(0, BODY) STEP2(2, BODY) STEP2(4, BODY)               \
    STEP2(6, BODY) STEP2(8, BODY) STEP2(10, BODY)              \
    STEP2(12, BODY) STEP2(14, BODY) STEP2(16, BODY)            \
  } while (0)

// Reduce one acc over rows (lane bits 3..5), store to red[(wv,jh,jj)][16].
#define RED1(AV, JJ)                                                 \
  do {                                                               \
    float4 a = AV;                                                   \
    a.x += __shfl_xor(a.x, 8);  a.y += __shfl_xor(a.y, 8);           \
    a.z += __shfl_xor(a.z, 8);  a.w += __shfl_xor(a.w, 8);           \
    a.x += __shfl_xor(a.x, 16); a.y += __shfl_xor(a.y, 16);          \
    a.z += __shfl_xor(a.z, 16); a.w += __shfl_xor(a.w, 16);          \
    a.x += __shfl_xor(a.x, 32); a.y += __shfl_xor(a.y, 32);          \
    a.z += __shfl_xor(a.z, 32); a.w += __shfl_xor(a.w, 32);          \
    if (lane < 8) {                                                  \
      float* dst = &red[(((wv << 1) + jh) * 5 + (JJ)) * 16 + q * 4]; \
      dst[0] = a.x; dst[1] = a.y; dst[2] = a.z; dst[3] = a.w;        \
    }                                                                \
  } while (0)

#define REDUCE_ALL() \
  do {               \
    RED1(acc0, 0);   \
    RED1(acc1, 1);   \
    RED1(acc2, 2);   \
    RED1(acc3, 3);   \
    RED1(acc4, 4);   \
    __syncthreads(); \
  } while (0)

#define LOAD_WQ()                                     \
  do {                                                \
    const float* _wp = &wsh[(jh * 5) * N_ + q * 4];   \
    wq0 = ld4(_wp);                                   \
    wq1 = ld4(_wp + N_);                              \
    wq2 = ld4(_wp + 2 * N_);                          \
    wq3 = ld4(_wp + 3 * N_);                          \
    wq4 = ld4(_wp + 4 * N_);                          \
  } while (0)

__device__ __forceinline__ float sum8(const float* __restrict__ red, int j,
                                      int n) {
  const int jh = (j >= 5) ? 1 : 0;
  const int jj = j - jh * 5;
  float s = 0.f;
#pragma unroll
  for (int w = 0; w < 8; ++w) s += red[(((w << 1) + jh) * 5 + jj) * 16 + n];
  return s;
}

__device__ __forceinline__ float squash16(float s) {
  // 16 pose components live in a 16-lane group (n = lane&15).
  float sq = s * s;
  sq += __shfl_xor(sq, 1);
  sq += __shfl_xor(sq, 2);
  sq += __shfl_xor(sq, 4);
  sq += __shfl_xor(sq, 8);
  return (sq / (1.f + sq)) * s * rsqrtf(sq + 1e-8f);
}

__global__ __launch_bounds__(TPB) void routing_one(
    const float* __restrict__ u, const float* __restrict__ bias,
    float* __restrict__ out) {
  const int tid = threadIdx.x;
  const int lane = tid & 63;
  const int wv = tid >> 6;
  // compute roles
  const int q = lane & 3;          // n-quad
  const int jh = (lane >> 2) & 1;  // j-half (0: j=0..4, 1: j=5..9)
  const int rc = lane >> 3;        // local row 0..7
  // loader roles
  const int jw = lane >> 5;        // j within pair
  const int rl = (lane >> 2) & 7;  // local row for load
  const int b = blockIdx.x;

  __shared__ __align__(16) float bufA[8 * WBUF];  // 40 KB
  __shared__ __align__(16) float bufB[8 * WBUF];  // 40 KB
  __shared__ float red[8 * 2 * 5 * 16];           // 5 KB
  __shared__ float wsh[J_ * N_];
  __shared__ float v0sh[J_ * N_];
  __shared__ float S0sh[J_ * N_];
  __shared__ float avg[J_];
  __shared__ float thr_s;

  const float* g0 = u + (size_t)b * J_ * I_ * N_ +
                    ((size_t)jw * I_ + (size_t)wv * 8 + rl) * N_ + q * 4;
  float* lA = bufA + wv * WBUF;
  float* lB = bufB + wv * WBUF;

  float4 t0, t1, t2, t3, t4;
  float4 acc0, acc1, acc2, acc3, acc4;
  float4 wq0 = make_float4(0.f, 0.f, 0.f, 0.f);
  float4 wq1 = wq0, wq2 = wq0, wq3 = wq0, wq4 = wq0;
  float mv0 = 0.f, mv1 = 0.f, mv2 = 0.f, mv3 = 0.f, mv4 = 0.f;

  // ---- pass 0: S0 = sum_i u ; v0 = squash(S0/J + bias) -------------------
  RUN_PASS(BODY_SUM);
  REDUCE_ALL();
  if (tid < J_ * N_) {
    const int j = tid >> 4, n = tid & 15;
    const float S0 = sum8(red, j, n);
    S0sh[tid] = S0;
    const float v0 = squash16(S0 * (1.f / (float)J_) + bias[j * N_ + n]);
    v0sh[tid] = v0;
    wsh[tid] = v0;
  }
  __syncthreads();
  LOAD_WQ();

  // ---- pass 1: c = softmax_j(u.v0); v1 = squash(s1+bias); threshold ------
  RUN_PASS(BODY_W);
  REDUCE_ALL();
  if (tid < J_ * N_) {
    const int j = tid >> 4, n = tid & 15;
    const float s1 = sum8(red, j, n) + bias[j * N_ + n];
    const float v1 = squash16(s1);
    const float w2 = v0sh[tid] + v1;
    wsh[tid] = w2;
    float pa = S0sh[tid] * w2;
    pa += __shfl_xor(pa, 1);
    pa += __shfl_xor(pa, 2);
    pa += __shfl_xor(pa, 4);
    pa += __shfl_xor(pa, 8);
    if (n == 0) avg[j] = pa * (1.f / (float)I_);
  }
  __syncthreads();
  if (tid == 0) {
    float a = avg[0];
    for (int jj = 1; jj < J_; ++jj) a = fmaxf(a, avg[jj]);
    float se = 0.f;
    for (int jj = 0; jj < J_; ++jj) se += expf(avg[jj] - a);
    thr_s = logf(0.1f) + a + logf(se);
  }
  __syncthreads();
  LOAD_WQ();
  mv0 = (avg[jh * 5 + 0] < thr_s) ? -1e30f : 0.f;
  mv1 = (avg[jh * 5 + 1] < thr_s) ? -1e30f : 0.f;
  mv2 = (avg[jh * 5 + 2] < thr_s) ? -1e30f : 0.f;
  mv3 = (avg[jh * 5 + 3] < thr_s) ? -1e30f : 0.f;
  mv4 = (avg[jh * 5 + 4] < thr_s) ? -1e30f : 0.f;

  // ---- pass 2: c = softmax_j(u.w + mv); out = del ? 0 : squash(s2) -------
  RUN_PASS(BODY_W);
  REDUCE_ALL();
  if (tid < J_ * N_) {
    const int j = tid >> 4, n = tid & 15;
    const float s2 = sum8(red, j, n) + bias[j * N_ + n];
    const float v2 = squash16(s2);
    const bool del = avg[j] < thr_s;
    out[(b * J_ + j) * N_ + n] = del ? 0.f : v2;
  }
}

extern "C" void kernel_launch(void* const* d_in, const int* in_sizes, int n_in,
                              void* d_out, int out_size, void* d_ws,
                              size_t ws_size, hipStream_t stream) {
  const float* u = (const float*)d_in[0];     // [B,J,I,N]
  const float* bias = (const float*)d_in[1];  // [J,N]
  // d_in[2] = iters (always 3; structure hardcoded)
  float* out = (float*)d_out;
  routing_one<<<B_, TPB, 0, stream>>>(u, bias, out);
}